// Round 1
// baseline (126.319 us; speedup 1.0000x reference)
//
#include <hip/hip_runtime.h>
#include <hip/hip_bf16.h>

// Fused attention: q = x1@Wq+bq, k = x2@Wk+bk, v = x2@Wv+bv (bf16, d padded 100->128),
// out = softmax(q k^T / 10) v. Flash-style, kv split 8-way + merge.
//
// ws layout: qg 2MB | kg 2MB | vT 2MB | pacc 8*100*8192*f32 (25MB) | pml 8*8192*float2 (512KB)

typedef __bf16 bf16x8 __attribute__((ext_vector_type(8)));
typedef __bf16 bf16x4 __attribute__((ext_vector_type(4)));
typedef float  f32x4  __attribute__((ext_vector_type(4)));
typedef short  short8_t __attribute__((ext_vector_type(8)));

#define SM_C 0.14426950408889634f   /* log2(e) / sqrt(100) */

__device__ __forceinline__ unsigned short f2bf(float f){
  unsigned u = __builtin_bit_cast(unsigned, f);
  u += 0x7FFFu + ((u >> 16) & 1u);
  return (unsigned short)(u >> 16);
}

#if __has_builtin(__builtin_amdgcn_global_load_lds)
#define HAVE_GLL 1
#endif

__device__ __forceinline__ void gload16(const short* g, short* l){
#ifdef HAVE_GLL
  __builtin_amdgcn_global_load_lds(
      (__attribute__((address_space(1))) void*)g,
      (__attribute__((address_space(3))) void*)l,
      16, 0, 0);
#else
  // fallback: reg round-trip; lds dest linear (wave base + lane*16 handled by caller giving
  // per-lane l already? caller passes wave base; emulate lane offset)
  const int lane = threadIdx.x & 63;
  *(short8_t*)(l + lane*8) = *(const short8_t*)(g);
#endif
}

// ---------------- projection kernel ----------------
__global__ __launch_bounds__(256) void proj_qkv(
    const float* __restrict__ x1, const float* __restrict__ x2,
    const float* __restrict__ Wq, const float* __restrict__ bq,
    const float* __restrict__ Wk, const float* __restrict__ bk,
    const float* __restrict__ Wv, const float* __restrict__ bv,
    short* __restrict__ qg, short* __restrict__ kg, short* __restrict__ vTg)
{
  __shared__ float xs[8][128];
  __shared__ float vs[8][104];
  const int z = blockIdx.y;
  const float* x = (z == 0) ? x1 : x2;
  const float* W = (z == 0) ? Wq : (z == 1) ? Wk : Wv;
  const float* b = (z == 0) ? bq : (z == 1) ? bk : bv;
  const int rb = blockIdx.x << 3;            // 8 rows per block
  const int t  = threadIdx.x;
  for (int i = t; i < 1024; i += 256) xs[i >> 7][i & 127] = x[(rb << 7) + i];
  __syncthreads();
  const int row = t >> 5, cs = t & 31;
  float4 a = make_float4(0.f, 0.f, 0.f, 0.f);
  if (cs < 25){
    a = *(const float4*)(b + (cs << 2));
#pragma unroll 4
    for (int i = 0; i < 128; ++i){
      const float xv = xs[row][i];
      const float4 wv = *(const float4*)(W + i*100 + (cs << 2));
      a.x = fmaf(xv, wv.x, a.x); a.y = fmaf(xv, wv.y, a.y);
      a.z = fmaf(xv, wv.z, a.z); a.w = fmaf(xv, wv.w, a.w);
    }
  }
  if (z < 2){
    short* o = (z == 0) ? qg : kg;
    short4 h;
    if (cs < 25){
      h.x = (short)f2bf(a.x); h.y = (short)f2bf(a.y);
      h.z = (short)f2bf(a.z); h.w = (short)f2bf(a.w);
      *(short4*)(o + ((rb + row) << 7) + (cs << 2)) = h;
    } else {
      h.x = 0; h.y = 0; h.z = 0; h.w = 0;    // zero-pad cols 100..127
      *(short4*)(o + ((rb + row) << 7) + 100 + ((cs - 25) << 2)) = h;
    }
  } else {
    if (cs < 25){
      vs[row][(cs<<2)+0] = a.x; vs[row][(cs<<2)+1] = a.y;
      vs[row][(cs<<2)+2] = a.z; vs[row][(cs<<2)+3] = a.w;
    }
    __syncthreads();
    if (t < 128){
      const int d = t;
      short8_t hv;
#pragma unroll
      for (int r = 0; r < 8; ++r) hv[r] = (d < 100) ? (short)f2bf(vs[r][d]) : (short)0;
      *(short8_t*)(vTg + (d << 13) + rb) = hv;   // vT[128][8192]
    }
  }
}

// ---------------- flash attention kernel ----------------
// 256 blocks = 32 qtiles x 8 kv-parts; 512 thr = 8 waves x 32 q rows; KB=64 per tile.
__global__ __launch_bounds__(512, 2) void attn_fwd(
    const short* __restrict__ qg, const short* __restrict__ kg,
    const short* __restrict__ vTg, float* __restrict__ pacc,
    float2* __restrict__ pml)
{
  __shared__ alignas(16) short sK[64*128];    // K tile, rows kv, 16B-block-swizzled
  __shared__ alignas(16) short sVT[128*64];   // V^T tile, rows d, 16B-block-swizzled
  const int tid  = threadIdx.x;
  const int w    = tid >> 6;
  const int lane = tid & 63;
  const int g    = lane >> 4;
  const int ln   = lane & 15;
  const int qt   = blockIdx.x & 31;
  const int part = blockIdx.x >> 5;
  const int qb   = qt*256 + w*32;

  // Q fragments (B-operand: lane holds Q[qb+sub*16+ln][ks*32 + g*8 + j])
  bf16x8 qf[2][4];
#pragma unroll
  for (int sub = 0; sub < 2; ++sub)
#pragma unroll
    for (int ks = 0; ks < 4; ++ks)
      qf[sub][ks] = *(const bf16x8*)(qg + (qb + sub*16 + ln)*128 + ks*32 + g*8);

  f32x4 acc[2][8];
#pragma unroll
  for (int sub = 0; sub < 2; ++sub)
#pragma unroll
    for (int db = 0; db < 8; ++db) acc[sub][db] = f32x4{0.f,0.f,0.f,0.f};
  float mrun[2] = {-3.0e38f, -3.0e38f};
  float lsum[2] = {0.f, 0.f};

  for (int t = 0; t < 16; ++t){
    const int kv0 = part*1024 + t*64;
    // ---- stage K (64x128 bf16) and V^T (128x64 bf16), source-swizzled, LDS linear ----
#pragma unroll
    for (int i = 0; i < 2; ++i){
      const int n = w*2 + i;                      // 0..15
      { const int r = n*4 + (lane >> 4);          // K tile row (kv)
        const int b = (lane & 15) ^ (r & 15);     // source 16B block
        gload16(kg + (kv0 + r)*128 + b*8, sK + n*512); }
      { const int r = n*8 + (lane >> 3);          // VT tile row (d)
        const int b = (lane & 7) ^ (r & 7);
        gload16(vTg + r*8192 + kv0 + b*8, sVT + n*512); }
    }
    __syncthreads();

    // ---- QK^T (swapped: mfma(K, Q)) -> st[sub][s] = scores^T, kv=16s+4g+r, q=ln ----
    f32x4 st[2][4];
#pragma unroll
    for (int s = 0; s < 4; ++s){ st[0][s] = f32x4{0.f,0.f,0.f,0.f}; st[1][s] = f32x4{0.f,0.f,0.f,0.f}; }
#pragma unroll
    for (int s = 0; s < 4; ++s){
      const int row = s*16 + ln;
#pragma unroll
      for (int ks = 0; ks < 4; ++ks){
        bf16x8 kf = *(const bf16x8*)(sK + row*128 + (((ks<<2) + g) ^ ln)*8);
        st[0][s] = __builtin_amdgcn_mfma_f32_16x16x32_bf16(kf, qf[0][ks], st[0][s], 0, 0, 0);
        st[1][s] = __builtin_amdgcn_mfma_f32_16x16x32_bf16(kf, qf[1][ks], st[1][s], 0, 0, 0);
      }
    }

    // ---- online softmax (per q row; lane's q = qb+sub*16+ln) ----
    bf16x8 pb[2][2];
#pragma unroll
    for (int sub = 0; sub < 2; ++sub){
      float mx = st[sub][0][0];
#pragma unroll
      for (int s = 0; s < 4; ++s)
#pragma unroll
        for (int r = 0; r < 4; ++r) mx = fmaxf(mx, st[sub][s][r]);
      mx = fmaxf(mx, __shfl_xor(mx, 16));
      mx = fmaxf(mx, __shfl_xor(mx, 32));
      const float mnew = fmaxf(mrun[sub], mx);
      const float f = exp2f((mrun[sub] - mnew) * SM_C);
      mrun[sub] = mnew;
      float ps = 0.f;
      float p[4][4];
#pragma unroll
      for (int s = 0; s < 4; ++s)
#pragma unroll
        for (int r = 0; r < 4; ++r){
          p[s][r] = exp2f((st[sub][s][r] - mnew) * SM_C);
          ps += p[s][r];
        }
      lsum[sub] = lsum[sub]*f + ps;
#pragma unroll
      for (int db = 0; db < 8; ++db) acc[sub][db] *= f;
#pragma unroll
      for (int c = 0; c < 2; ++c){
        short8_t pk;
#pragma unroll
        for (int r = 0; r < 4; ++r){
          pk[r]   = (short)f2bf(p[2*c][r]);      // k' slots j<4  -> kv = 32c+4g+j
          pk[4+r] = (short)f2bf(p[2*c+1][r]);    // k' slots j>=4 -> kv = 32c+16+4g+(j-4)
        }
        pb[sub][c] = __builtin_bit_cast(bf16x8, pk);
      }
    }

    // ---- PV: out^T += V^T x P^T (A slots match pb's kv mapping) ----
#pragma unroll
    for (int c = 0; c < 2; ++c)
#pragma unroll
      for (int db = 0; db < 8; ++db){
        const int row = db*16 + ln;
        const int l7 = ln & 7;
        bf16x4 v0 = *(const bf16x4*)(sVT + row*64 + ((((c<<2)   + (g>>1)) ^ l7) << 3) + ((g&1) << 2));
        bf16x4 v1 = *(const bf16x4*)(sVT + row*64 + ((((c<<2)+2 + (g>>1)) ^ l7) << 3) + ((g&1) << 2));
        bf16x8 vf;
#pragma unroll
        for (int j = 0; j < 4; ++j){ vf[j] = v0[j]; vf[4+j] = v1[j]; }
        acc[0][db] = __builtin_amdgcn_mfma_f32_16x16x32_bf16(vf, pb[0][c], acc[0][db], 0, 0, 0);
        acc[1][db] = __builtin_amdgcn_mfma_f32_16x16x32_bf16(vf, pb[1][c], acc[1][db], 0, 0, 0);
      }
    __syncthreads();
  }

  // ---- epilogue: finish row sums, write partials ----
#pragma unroll
  for (int sub = 0; sub < 2; ++sub){
    float ls = lsum[sub];
    ls += __shfl_xor(ls, 16);
    ls += __shfl_xor(ls, 32);
    lsum[sub] = ls;
  }
#pragma unroll
  for (int sub = 0; sub < 2; ++sub)
#pragma unroll
    for (int db = 0; db < 8; ++db)
#pragma unroll
      for (int r = 0; r < 4; ++r){
        const int d = db*16 + g*4 + r;
        if (d < 100)
          pacc[((part*100 + d) << 13) + qb + sub*16 + ln] = acc[sub][db][r];
      }
  if (g == 0) pml[(part << 13) + qb + ln]      = make_float2(mrun[0], lsum[0]);
  if (g == 1) pml[(part << 13) + qb + 16 + ln] = make_float2(mrun[1], lsum[1]);
}

// ---------------- merge kernel ----------------
__global__ __launch_bounds__(256) void merge_parts(
    const float* __restrict__ pacc, const float2* __restrict__ pml,
    float* __restrict__ out)
{
  __shared__ float ol[64*101];
  const int t  = threadIdx.x;
  const int tq = t & 63;
  const int td = t >> 6;       // 0..3 (wave-uniform)
  const int qb = blockIdx.x << 6;
  const int q  = qb + tq;
  float m8[8], l8[8];
  float mstar = -3.0e38f;
#pragma unroll
  for (int p = 0; p < 8; ++p){
    float2 ml = pml[(p << 13) + q];
    m8[p] = ml.x; l8[p] = ml.y;
    mstar = fmaxf(mstar, ml.x);
  }
  float L = 0.f; float w8[8];
#pragma unroll
  for (int p = 0; p < 8; ++p){ w8[p] = exp2f((m8[p] - mstar) * SM_C); L += l8[p]*w8[p]; }
  const float inv = 1.0f / L;
  for (int dd = 0; dd < 25; ++dd){
    const int d = td*25 + dd;      // 0..99
    float s = 0.f;
#pragma unroll
    for (int p = 0; p < 8; ++p) s += pacc[((p*100 + d) << 13) + q] * w8[p];
    ol[tq*101 + d] = s * inv;
  }
  __syncthreads();
  for (int idx = t; idx < 6400; idx += 256){
    const int q2 = idx / 100, d2 = idx - q2*100;
    out[(qb + q2)*100 + d2] = ol[q2*101 + d2];
  }
}

// ---------------- launcher ----------------
extern "C" void kernel_launch(void* const* d_in, const int* in_sizes, int n_in,
                              void* d_out, int out_size, void* d_ws, size_t ws_size,
                              hipStream_t stream)
{
  const float* x1 = (const float*)d_in[0];
  const float* x2 = (const float*)d_in[1];
  const float* Wq = (const float*)d_in[2];
  const float* bq = (const float*)d_in[3];
  const float* Wk = (const float*)d_in[4];
  const float* bk = (const float*)d_in[5];
  const float* Wv = (const float*)d_in[6];
  const float* bv = (const float*)d_in[7];
  char* ws = (char*)d_ws;
  short*  qg   = (short*)ws;                                  // 2 MB
  short*  kg   = (short*)(ws + (1u << 21));                   // 2 MB
  short*  vTg  = (short*)(ws + (2u << 21));                   // 2 MB
  float*  pacc = (float*)(ws + (3u << 21));                   // 8*100*8192*4 B
  float2* pml  = (float2*)(ws + (3u << 21) + 8u*100u*8192u*4u);
  float*  out  = (float*)d_out;

  proj_qkv<<<dim3(1024, 3), 256, 0, stream>>>(x1, x2, Wq, bq, Wk, bk, Wv, bv, qg, kg, vTg);
  attn_fwd<<<256, 512, 0, stream>>>(qg, kg, vTg, pacc, pml);
  merge_parts<<<128, 256, 0, stream>>>(pacc, pml, out);
}

// Round 2
// 84.567 us; speedup vs baseline: 1.4937x; 1.4937x over previous
//
#include <hip/hip_runtime.h>
#include <hip/hip_bf16.h>

// Fused attention: q = x1@Wq+bq, k = x2@Wk+bk, v = x2@Wv+bv (bf16, d padded 100->128),
// out = softmax(q k^T / 10) v. Flash-style, kv split 8-way + merge.
// ws: qg 2MB | kg 2MB | vT2 2MB (k-slot permuted) | pacc 8*100*8192*f32 | pml 8*8192*float2

typedef __bf16 bf16x8 __attribute__((ext_vector_type(8)));
typedef float  f32x4  __attribute__((ext_vector_type(4)));
typedef short  short8_t __attribute__((ext_vector_type(8)));

#define SM_C 0.14426950408889634f   /* log2(e) / sqrt(100) */

#if __has_builtin(__builtin_amdgcn_global_load_lds)
#define HAVE_GLL 1
#endif

__device__ __forceinline__ void gload16(const short* g, short* l){
#ifdef HAVE_GLL
  __builtin_amdgcn_global_load_lds(
      (__attribute__((address_space(1))) void*)g,
      (__attribute__((address_space(3))) void*)l,
      16, 0, 0);
#else
  *(short8_t*)(l + (threadIdx.x & 63)*8) = *(const short8_t*)(g);
#endif
}

__device__ __forceinline__ short bf(float f){ return __builtin_bit_cast(short, (__bf16)f); }

// ---------------- projection kernel: 16 rows/block ----------------
__global__ __launch_bounds__(256) void proj_qkv(
    const float* __restrict__ x1, const float* __restrict__ x2,
    const float* __restrict__ Wq, const float* __restrict__ bq,
    const float* __restrict__ Wk, const float* __restrict__ bk,
    const float* __restrict__ Wv, const float* __restrict__ bv,
    short* __restrict__ qg, short* __restrict__ kg, short* __restrict__ vT2)
{
  __shared__ float xs[16][128];
  __shared__ float vs[16][104];
  const int z = blockIdx.y;
  const float* x = (z == 0) ? x1 : x2;
  const float* W = (z == 0) ? Wq : (z == 1) ? Wk : Wv;
  const float* b = (z == 0) ? bq : (z == 1) ? bk : bv;
  const int rb = blockIdx.x << 4;            // 16 rows per block
  const int t  = threadIdx.x;
  for (int i = t; i < 2048; i += 256) xs[i >> 7][i & 127] = x[(rb << 7) + i];
  __syncthreads();
  const int rw = t >> 5, cs = t & 31;        // rows rw, rw+8; cols cs*4..cs*4+3
  float4 a0 = make_float4(0.f,0.f,0.f,0.f), a1 = a0;
  if (cs < 25){
    a0 = *(const float4*)(b + (cs << 2)); a1 = a0;
#pragma unroll 8
    for (int i = 0; i < 128; ++i){
      const float4 wv = *(const float4*)(W + i*100 + (cs << 2));
      const float xv0 = xs[rw][i], xv1 = xs[rw+8][i];
      a0.x = fmaf(xv0, wv.x, a0.x); a0.y = fmaf(xv0, wv.y, a0.y);
      a0.z = fmaf(xv0, wv.z, a0.z); a0.w = fmaf(xv0, wv.w, a0.w);
      a1.x = fmaf(xv1, wv.x, a1.x); a1.y = fmaf(xv1, wv.y, a1.y);
      a1.z = fmaf(xv1, wv.z, a1.z); a1.w = fmaf(xv1, wv.w, a1.w);
    }
  }
  if (z < 2){
    short* o = (z == 0) ? qg : kg;
    if (cs < 25){
      short4 h0, h1;
      h0.x=bf(a0.x); h0.y=bf(a0.y); h0.z=bf(a0.z); h0.w=bf(a0.w);
      h1.x=bf(a1.x); h1.y=bf(a1.y); h1.z=bf(a1.z); h1.w=bf(a1.w);
      *(short4*)(o + ((rb + rw)     << 7) + (cs << 2)) = h0;
      *(short4*)(o + ((rb + rw + 8) << 7) + (cs << 2)) = h1;
    } else {
      short4 hz; hz.x=0; hz.y=0; hz.z=0; hz.w=0;   // zero-pad cols 100..127
      *(short4*)(o + ((rb + rw)     << 7) + 100 + ((cs - 25) << 2)) = hz;
      *(short4*)(o + ((rb + rw + 8) << 7) + 100 + ((cs - 25) << 2)) = hz;
    }
  } else {
    if (cs < 25){
      vs[rw  ][(cs<<2)+0]=a0.x; vs[rw  ][(cs<<2)+1]=a0.y; vs[rw  ][(cs<<2)+2]=a0.z; vs[rw  ][(cs<<2)+3]=a0.w;
      vs[rw+8][(cs<<2)+0]=a1.x; vs[rw+8][(cs<<2)+1]=a1.y; vs[rw+8][(cs<<2)+2]=a1.z; vs[rw+8][(cs<<2)+3]=a1.w;
    }
    __syncthreads();
    if (t < 128){
      const int d = t;
      // write 16 kv values (rb..rb+15) into k-slot-permuted layout:
      // within each 64-group: idx = c*32 + g*8 + j  <->  kv = c*32 + 4g + (j<4 ? j : 12+j)
#pragma unroll
      for (int h = 0; h < 4; ++h){
        const int kv0 = rb + h*4;
        const int o32 = kv0 & 31;
        const int idx = (o32 < 16) ? ((o32 >> 2) << 3) : ((((o32 - 16) >> 2) << 3) + 4);
        short4 hv;
        float f0 = (d<100)? vs[(kv0  )-rb+0>0? (kv0-rb):(kv0-rb)][d] : 0.f; (void)f0;
        const int r0 = kv0 - rb;
        hv.x = (d<100)? bf(vs[r0+0][d]) : (short)0;
        hv.y = (d<100)? bf(vs[r0+1][d]) : (short)0;
        hv.z = (d<100)? bf(vs[r0+2][d]) : (short)0;
        hv.w = (d<100)? bf(vs[r0+3][d]) : (short)0;
        *(short4*)(vT2 + (d << 13) + (kv0 & ~63) + ((kv0 >> 5) & 1)*32 + idx) = hv;
      }
    }
  }
}

// ---------------- flash attention: 512 blocks = 64 qtiles x 8 parts, 4 waves ----------------
__global__ __launch_bounds__(256, 2) void attn_fwd(
    const short* __restrict__ qg, const short* __restrict__ kg,
    const short* __restrict__ vT2, float* __restrict__ pacc,
    float2* __restrict__ pml)
{
  __shared__ alignas(16) short sK[2][64*128];    // 2 x 16KB, 16B-block swizzled (XOR r&15)
  __shared__ alignas(16) short sVT[2][112*64];   // 2 x 14KB, 16B-block swizzled (XOR r&7)
  const int tid  = threadIdx.x;
  const int w    = tid >> 6;
  const int lane = tid & 63;
  const int g    = lane >> 4;
  const int ln   = lane & 15;
  const int qt   = blockIdx.x & 63;
  const int part = blockIdx.x >> 6;
  const int qb   = qt*128 + w*32;

  // Q fragments: lane holds Q[qb+sub*16+ln][ks*32 + g*8 + j]
  bf16x8 qf[2][4];
#pragma unroll
  for (int sub = 0; sub < 2; ++sub)
#pragma unroll
    for (int ks = 0; ks < 4; ++ks)
      qf[sub][ks] = *(const bf16x8*)(qg + (qb + sub*16 + ln)*128 + ks*32 + g*8);

  f32x4 acc[2][7];
#pragma unroll
  for (int sub = 0; sub < 2; ++sub)
#pragma unroll
    for (int db = 0; db < 7; ++db) acc[sub][db] = f32x4{0.f,0.f,0.f,0.f};
  float mrun[2] = {-3.0e38f, -3.0e38f};
  float lsum[2] = {0.f, 0.f};

  auto stage = [&](int kv0, int buf){
#pragma unroll
    for (int i = 0; i < 4; ++i){              // K: 16 x 1KB
      const int id = w + (i << 2);
      const int r  = (id << 2) + (lane >> 4);
      const int bx = (lane & 15) ^ (r & 15);
      gload16(kg + (kv0 + r)*128 + bx*8, &sK[buf][id << 9]);
    }
#pragma unroll
    for (int i = 0; i < 3; ++i){              // VT rows 0..95: 12 x 1KB
      const int id = w + (i << 2);
      const int r  = (id << 3) + (lane >> 3);
      const int bx = (lane & 7) ^ (r & 7);
      gload16(vT2 + r*8192 + kv0 + bx*8, &sVT[buf][id << 9]);
    }
    if (w < 2){                               // VT rows 96..111: 2 x 1KB
      const int id = 12 + w;
      const int r  = (id << 3) + (lane >> 3);
      const int bx = (lane & 7) ^ (r & 7);
      gload16(vT2 + r*8192 + kv0 + bx*8, &sVT[buf][id << 9]);
    }
  };

  const int kvbase = part << 10;
  stage(kvbase, 0);
  int cur = 0;
  for (int t = 0; t < 16; ++t){
    __syncthreads();                          // staging of buf[cur] complete
    if (t < 15) stage(kvbase + ((t+1) << 6), cur ^ 1);
    const short* sKc = sK[cur];
    const short* sVc = sVT[cur];

    // ---- QK^T (swapped): st[sub][s][r] = score[kv=16s+4g+r][q=qb+sub*16+ln] ----
    f32x4 st[2][4];
#pragma unroll
    for (int s = 0; s < 4; ++s){ st[0][s] = f32x4{0.f,0.f,0.f,0.f}; st[1][s] = f32x4{0.f,0.f,0.f,0.f}; }
#pragma unroll
    for (int s = 0; s < 4; ++s){
      const int rbase = (s*16 + ln) << 7;
#pragma unroll
      for (int ks = 0; ks < 4; ++ks){
        bf16x8 kf = *(const bf16x8*)(sKc + rbase + ((((ks<<2) + g) ^ ln) << 3));
        st[0][s] = __builtin_amdgcn_mfma_f32_16x16x32_bf16(kf, qf[0][ks], st[0][s], 0, 0, 0);
        st[1][s] = __builtin_amdgcn_mfma_f32_16x16x32_bf16(kf, qf[1][ks], st[1][s], 0, 0, 0);
      }
    }

    // ---- online softmax with defer-max (THR = 8 score units -> P <= e^0.8) ----
    bf16x8 pb[2][2];
#pragma unroll
    for (int sub = 0; sub < 2; ++sub){
      float mx = st[sub][0][0];
#pragma unroll
      for (int s = 0; s < 4; ++s)
#pragma unroll
        for (int r = 0; r < 4; ++r) mx = fmaxf(mx, st[sub][s][r]);
      mx = fmaxf(mx, __shfl_xor(mx, 16));
      mx = fmaxf(mx, __shfl_xor(mx, 32));
      if (!__all(mx - mrun[sub] <= 8.0f)){
        const float mnew = fmaxf(mrun[sub], mx);
        const float f = exp2f((mrun[sub] - mnew) * SM_C);
        lsum[sub] *= f;
#pragma unroll
        for (int db = 0; db < 7; ++db) acc[sub][db] *= f;
        mrun[sub] = mnew;
      }
      const float mc = mrun[sub] * SM_C;
      float p[4][4]; float ps = 0.f;
#pragma unroll
      for (int s = 0; s < 4; ++s)
#pragma unroll
        for (int r = 0; r < 4; ++r){
          p[s][r] = exp2f(fmaf(st[sub][s][r], SM_C, -mc));
          ps += p[s][r];
        }
      lsum[sub] += ps;
#pragma unroll
      for (int c = 0; c < 2; ++c){
        bf16x8 pv;
#pragma unroll
        for (int r = 0; r < 4; ++r){
          pv[r]   = (__bf16)p[2*c][r];       // k-slot j<4  -> kv = 32c+4g+j
          pv[4+r] = (__bf16)p[2*c+1][r];     // k-slot j>=4 -> kv = 32c+16+4g+(j-4)
        }
        pb[sub][c] = pv;
      }
    }

    // ---- PV: out^T += V^T x P^T; single b128 A-frag via permuted layout ----
#pragma unroll
    for (int c = 0; c < 2; ++c)
#pragma unroll
      for (int db = 0; db < 7; ++db){
        const int row = db*16 + ln;
        bf16x8 vf = *(const bf16x8*)(sVc + (row << 6) + (((((c<<2) + g)) ^ (ln & 7)) << 3));
        acc[0][db] = __builtin_amdgcn_mfma_f32_16x16x32_bf16(vf, pb[0][c], acc[0][db], 0, 0, 0);
        acc[1][db] = __builtin_amdgcn_mfma_f32_16x16x32_bf16(vf, pb[1][c], acc[1][db], 0, 0, 0);
      }
    cur ^= 1;
  }

  // ---- epilogue ----
#pragma unroll
  for (int sub = 0; sub < 2; ++sub){
    float ls = lsum[sub];
    ls += __shfl_xor(ls, 16);
    ls += __shfl_xor(ls, 32);
    lsum[sub] = ls;
  }
#pragma unroll
  for (int sub = 0; sub < 2; ++sub)
#pragma unroll
    for (int db = 0; db < 7; ++db)
#pragma unroll
      for (int r = 0; r < 4; ++r){
        const int d = db*16 + g*4 + r;
        if (d < 100)
          pacc[((part*100 + d) << 13) + qb + sub*16 + ln] = acc[sub][db][r];
      }
  if (g == 0) pml[(part << 13) + qb + ln]      = make_float2(mrun[0], lsum[0]);
  if (g == 1) pml[(part << 13) + qb + 16 + ln] = make_float2(mrun[1], lsum[1]);
}

// ---------------- merge kernel: 128 qblocks x 5 d-chunks ----------------
__global__ __launch_bounds__(256) void merge_parts(
    const float* __restrict__ pacc, const float2* __restrict__ pml,
    float* __restrict__ out)
{
  __shared__ float ol[64][21];
  const int t  = threadIdx.x;
  const int tq = t & 63;
  const int td = t >> 6;                 // 0..3 (wave-uniform)
  const int qb = blockIdx.x << 6;
  const int db = blockIdx.y * 20;
  const int q  = qb + tq;
  float m8[8], l8[8];
  float mstar = -3.0e38f;
#pragma unroll
  for (int p = 0; p < 8; ++p){
    float2 ml = pml[(p << 13) + q];
    m8[p] = ml.x; l8[p] = ml.y;
    mstar = fmaxf(mstar, ml.x);
  }
  float L = 0.f; float w8[8];
#pragma unroll
  for (int p = 0; p < 8; ++p){ w8[p] = exp2f((m8[p] - mstar) * SM_C); L += l8[p]*w8[p]; }
  const float inv = 1.0f / L;
#pragma unroll
  for (int i = 0; i < 5; ++i){
    const int d = db + td*5 + i;
    float s = 0.f;
#pragma unroll
    for (int p = 0; p < 8; ++p) s += pacc[((p*100 + d) << 13) + q] * w8[p];
    ol[tq][td*5 + i] = s * inv;
  }
  __syncthreads();
  for (int idx = t; idx < 1280; idx += 256){
    const int q2 = idx / 20, d2 = idx - q2*20;
    out[(qb + q2)*100 + db + d2] = ol[q2][d2];
  }
}

// ---------------- launcher ----------------
extern "C" void kernel_launch(void* const* d_in, const int* in_sizes, int n_in,
                              void* d_out, int out_size, void* d_ws, size_t ws_size,
                              hipStream_t stream)
{
  const float* x1 = (const float*)d_in[0];
  const float* x2 = (const float*)d_in[1];
  const float* Wq = (const float*)d_in[2];
  const float* bq = (const float*)d_in[3];
  const float* Wk = (const float*)d_in[4];
  const float* bk = (const float*)d_in[5];
  const float* Wv = (const float*)d_in[6];
  const float* bv = (const float*)d_in[7];
  char* ws = (char*)d_ws;
  short*  qg   = (short*)ws;                                  // 2 MB
  short*  kg   = (short*)(ws + (1u << 21));                   // 2 MB
  short*  vT2  = (short*)(ws + (2u << 21));                   // 2 MB (permuted)
  float*  pacc = (float*)(ws + (3u << 21));                   // 8*100*8192*4 B
  float2* pml  = (float2*)(ws + (3u << 21) + 8u*100u*8192u*4u);
  float*  out  = (float*)d_out;

  proj_qkv<<<dim3(512, 3), 256, 0, stream>>>(x1, x2, Wq, bq, Wk, bk, Wv, bv, qg, kg, vT2);
  attn_fwd<<<512, 256, 0, stream>>>(qg, kg, vT2, pacc, pml);
  merge_parts<<<dim3(128, 5), 256, 0, stream>>>(pacc, pml, out);
}